// Round 4
// baseline (454.426 us; speedup 1.0000x reference)
//
#include <hip/hip_runtime.h>
#include <hip/hip_fp16.h>
#include <cstdint>

// LocalAttention fused kernel, round 9: T=256 -> T=512 (occupancy 12 -> 24
// waves/CU at unchanged LDS).
//
// Round-8 post-mortem: wv2-liveness spill confirmed fixed (kernel ~152us,
// out of rocprof top-5). Remaining gap to roofline (~49us HBM / ~31us VALU)
// is latency: 3 blocks/CU x 4 waves = 12 waves/CU only.
// This round: same G_=4 / 52.5KB LDS, but 512-thread blocks -> 3 blocks/CU
// x 8 waves = 24 waves/CU (75% cap). Per-thread work halves in every phase.
// VGPR must be <= 512/6 = 85 for 6 waves/SIMD: enforced via
// __launch_bounds__(512,6); protected by loading Wq/Wv at use (r8 lesson)
// and shrinking Phase C's wk cache to [2][16] (thread owns 2 j's).
// Phase B/G: c split across extra threads (2 c's/thread), partials still
// [4js][4c][128] = 8KB in s_ts. Phase F: at T=512 two waves share a c-slab,
// so the read->write overlay needs an explicit barrier between accumulate
// and store (the old one-wave-per-c WAR argument no longer holds).
//
// Algebra (exact in real arithmetic):
//   energy[h,n] = sum_j an[n,j] * t[h,j],  t[h,j] = 0.25 * sum_d' q[h,d'] Wk[j,h*16+d']
//     (bk constant over n -> cancels in softmax)
//   ctx[h,d'] = sum_j s[h,j] * Wv[j,h*16+d'] + (sum_n attnm[h,n]) * bv[h,d']
//     with s[h,:] = attnm[h,:] @ an

#define B_ 16
#define C_ 1024
#define N_ 32
#define H_ 8
#define D_ 128
#define G_ 4
#define T_ 512

typedef unsigned short u16;
typedef unsigned int u32;
typedef __fp16 hw2 __attribute__((ext_vector_type(2)));   // matches builtin sigs

__device__ __forceinline__ u32 pkrtz(float a, float b) {
    hw2 r = __builtin_amdgcn_cvt_pkrtz(a, b);
    return __builtin_bit_cast(u32, r);
}
__device__ __forceinline__ float fdot2(u32 a, u32 b, float c) {
#if __has_builtin(__builtin_amdgcn_fdot2)
    return __builtin_amdgcn_fdot2(__builtin_bit_cast(hw2, a),
                                  __builtin_bit_cast(hw2, b), c, false);
#else
    float2 A = __half22float2(__builtin_bit_cast(__half2, a));
    float2 B = __half22float2(__builtin_bit_cast(__half2, b));
    return fmaf(A.y, B.y, fmaf(A.x, B.x, c));
#endif
}
__device__ __forceinline__ __half2 fma2(u32 a, u32 b, __half2 c) {
    return __hfma2(__builtin_bit_cast(__half2, a),
                   __builtin_bit_cast(__half2, b), c);
}
__device__ __forceinline__ float swishf(float x) {
    float s = __builtin_amdgcn_rcpf(1.0f + __expf(-x));
    return x * s;
}

__global__ __launch_bounds__(T_, 6)
void la_kernel(const float* __restrict__ aq_g,  const float* __restrict__ an_g,
               const float* __restrict__ dist_g, const float* __restrict__ mask_g,
               const float* __restrict__ wq_g,  const float* __restrict__ bq_g,
               const float* __restrict__ wk_g,
               const float* __restrict__ wv_g,  const float* __restrict__ bv_g,
               const float* __restrict__ wf_g,  const float* __restrict__ bfb_g,
               float* __restrict__ attn_o, float* __restrict__ ctx_o)
{
    // LDS: 34816(s_an) + 8704(s_ts) + 2560(s_q) + 4224(s_eat) + 512+512+128+512+512
    //    = 52,480 B  -> 3 blocks/CU (3 x 8 waves = 24 waves/CU)
    __shared__ __align__(16) u16   s_an[G_ * N_ * 136];   // gated neighbors f16; per-c f32 s-slab after F
    __shared__ __align__(16) u32   s_ts[G_ * H_ * 68];    // B-partials(f32) / t32(f16 pairs) / G-partials(f32)
    __shared__ __align__(16) float s_q[G_][H_ * 20];      // projected query (unscaled), head stride 20
    __shared__ __align__(16) float s_eat[G_][H_][33];     // aq staging (ph0..B) -> energy f32 (D/E) -> am pairs (F)
    __shared__ float s_dist[G_][N_];
    __shared__ float s_mask[G_][N_];
    __shared__ float s_asum[G_][H_];
    __shared__ __align__(16) float s_wf[D_];
    __shared__ __align__(16) float s_bfb[D_];

    const int tid = threadIdx.x;
    const int b   = blockIdx.x >> 8;          // 256 c-groups per b
    const int c0  = (blockIdx.x & 255) << 2;  // G_=4 c's per block

    // ---- Phase 0: stage small tensors ----
    float* s_aqf = (float*)s_eat;             // [c*128+d], first 2048 B of the s_eat slab
    if (tid < D_) {
        s_wf[tid]  = wf_g[tid];
        s_bfb[tid] = bfb_g[tid];
        int c = tid >> 5, n = tid & 31;
        int gi = (b * C_ + c0 + c) * N_ + n;
        s_dist[c][n] = dist_g[gi];
        s_mask[c][n] = mask_g[gi];
    }
    s_aqf[tid] = aq_g[(b * C_ + c0 + (tid >> 7)) * D_ + (tid & 127)];
    __syncthreads();

    // ---- Phase A: stream + swish-gate atom_neighbor -> s_an (f16 pairs) ----
    {
        const float4* gan = (const float4*)(an_g + (size_t)(b * C_ + c0) * N_ * D_);
        #pragma unroll
        for (int k = 0; k < 8; k++) {
            int ci = k * T_ + tid;                  // float4 chunk index, 4096 total
            float4 v = gan[ci];
            int d4 = ci & 31, n = (ci >> 5) & 31, c = ci >> 10;
            float dist = s_dist[c][n];
            int d0 = d4 << 2;
            float4 wf = *(const float4*)&s_wf[d0];
            float4 bb = *(const float4*)&s_bfb[d0];
            float g0 = swishf(fmaf(dist, wf.x, bb.x));
            float g1 = swishf(fmaf(dist, wf.y, bb.y));
            float g2 = swishf(fmaf(dist, wf.z, bb.z));
            float g3 = swishf(fmaf(dist, wf.w, bb.w));
            u32 o0 = pkrtz(v.x * g0, v.y * g1);
            u32 o1 = pkrtz(v.z * g2, v.w * g3);
            *(uint2*)(s_an + (c * N_ + n) * 136 + d0) = make_uint2(o0, o1);
        }
    }

    // ---- Phase B: q partials — thread (op, js4, ch): od pair 2op, j-rows
    // js4*32..+32, c in {2ch, 2ch+1}. Wq loaded at use (L2-warm; no live
    // register array — r8 lesson). ----
    {
        const int op  = tid & 63;
        const int js4 = (tid >> 6) & 3;
        const int ch  = tid >> 8;
        const int cA  = ch * 2, cB = cA + 1;
        float a0A = 0.f, a1A = 0.f, a0B = 0.f, a1B = 0.f;
        #pragma unroll
        for (int i4 = 0; i4 < 8; i4++) {
            int j = js4 * 32 + i4 * 4;
            float2 w0 = ((const float2*)(wq_g + (size_t)(j + 0) * D_))[op];
            float2 w1 = ((const float2*)(wq_g + (size_t)(j + 1) * D_))[op];
            float2 w2 = ((const float2*)(wq_g + (size_t)(j + 2) * D_))[op];
            float2 w3 = ((const float2*)(wq_g + (size_t)(j + 3) * D_))[op];
            float4 aA = *(const float4*)&s_aqf[cA * D_ + j];
            float4 aB = *(const float4*)&s_aqf[cB * D_ + j];
            a0A = fmaf(aA.x, w0.x, a0A); a1A = fmaf(aA.x, w0.y, a1A);
            a0A = fmaf(aA.y, w1.x, a0A); a1A = fmaf(aA.y, w1.y, a1A);
            a0A = fmaf(aA.z, w2.x, a0A); a1A = fmaf(aA.z, w2.y, a1A);
            a0A = fmaf(aA.w, w3.x, a0A); a1A = fmaf(aA.w, w3.y, a1A);
            a0B = fmaf(aB.x, w0.x, a0B); a1B = fmaf(aB.x, w0.y, a1B);
            a0B = fmaf(aB.y, w1.x, a0B); a1B = fmaf(aB.y, w1.y, a1B);
            a0B = fmaf(aB.z, w2.x, a0B); a1B = fmaf(aB.z, w2.y, a1B);
            a0B = fmaf(aB.w, w3.x, a0B); a1B = fmaf(aB.w, w3.y, a1B);
        }
        float* s_part = (float*)s_ts;   // [js4][4c][128] f32 = 8 KB
        *(float2*)&s_part[(js4 * 4 + cA) * D_ + 2 * op] = make_float2(a0A, a1A);
        *(float2*)&s_part[(js4 * 4 + cB) * D_ + 2 * op] = make_float2(a0B, a1B);
    }
    __syncthreads();

    // ---- Phase B2: reduce partials -> s_q (head stride 20); single pass ----
    {
        const float* s_part = (const float*)s_ts;
        int c = tid >> 7, od = tid & 127;
        float sum = s_part[(0 * 4 + c) * D_ + od] + s_part[(1 * 4 + c) * D_ + od]
                  + s_part[(2 * 4 + c) * D_ + od] + s_part[(3 * 4 + c) * D_ + od];
        s_q[c][(od >> 4) * 20 + (od & 15)] = sum + bq_g[od];
    }
    __syncthreads();

    // ---- Phase C: t[c,h,j] = 0.25*sum_d' q*Wk -> f16 pairs in t32 ----
    // thread (h, a, half): pair p = a + 32*half, j = 2p, 2p+1. wk[2][16]=32 regs.
    {
        u32* t32 = s_ts;                   // [c*8+h][68] u32 (f16 pairs)
        int h = tid & 7, a = (tid >> 3) & 31, half = tid >> 8;
        int p = a + 32 * half;             // pair index 0..63
        float wk[2][16];
        #pragma unroll
        for (int jj = 0; jj < 2; jj++) {
            int j = 2 * p + jj;
            const float4* pk = (const float4*)(wk_g + j * D_ + h * 16);
            float4 k0 = pk[0], k1 = pk[1], k2 = pk[2], k3 = pk[3];
            wk[jj][0]  = k0.x; wk[jj][1]  = k0.y; wk[jj][2]  = k0.z; wk[jj][3]  = k0.w;
            wk[jj][4]  = k1.x; wk[jj][5]  = k1.y; wk[jj][6]  = k1.z; wk[jj][7]  = k1.w;
            wk[jj][8]  = k2.x; wk[jj][9]  = k2.y; wk[jj][10] = k2.z; wk[jj][11] = k2.w;
            wk[jj][12] = k3.x; wk[jj][13] = k3.y; wk[jj][14] = k3.z; wk[jj][15] = k3.w;
        }
        #pragma unroll
        for (int c = 0; c < G_; c++) {
            const float4* pq = (const float4*)&s_q[c][h * 20];   // 80B base: 16B aligned
            float4 q0 = pq[0], q1 = pq[1], q2 = pq[2], q3 = pq[3];
            float acc[2];
            #pragma unroll
            for (int jj = 0; jj < 2; jj++) {
                float v = 0.f;
                v = fmaf(q0.x, wk[jj][0],  v);
                v = fmaf(q0.y, wk[jj][1],  v);
                v = fmaf(q0.z, wk[jj][2],  v);
                v = fmaf(q0.w, wk[jj][3],  v);
                v = fmaf(q1.x, wk[jj][4],  v);
                v = fmaf(q1.y, wk[jj][5],  v);
                v = fmaf(q1.z, wk[jj][6],  v);
                v = fmaf(q1.w, wk[jj][7],  v);
                v = fmaf(q2.x, wk[jj][8],  v);
                v = fmaf(q2.y, wk[jj][9],  v);
                v = fmaf(q2.z, wk[jj][10], v);
                v = fmaf(q2.w, wk[jj][11], v);
                v = fmaf(q3.x, wk[jj][12], v);
                v = fmaf(q3.y, wk[jj][13], v);
                v = fmaf(q3.z, wk[jj][14], v);
                v = fmaf(q3.w, wk[jj][15], v);
                acc[jj] = v * 0.25f;
            }
            t32[(c * 8 + h) * 68 + p] = pkrtz(acc[0], acc[1]);  // pair p = (j,j+1)
        }
    }
    __syncthreads();

    // ---- Phase D: energy via v_dot2_f32_f16, fp32 accumulate ----
    // thread (c, h, n0): n in {n0, n0+16}
    {
        const u32* t32 = s_ts;
        int c = tid >> 7, h = (tid >> 4) & 7, n0 = tid & 15;
        const uint4* trow = (const uint4*)(t32 + (c * 8 + h) * 68);
        float acc[2] = {0.f, 0.f};
        #pragma unroll
        for (int jc = 0; jc < 16; jc++) {
            uint4 t4 = trow[jc];               // 8 f16 = j 8jc..8jc+7
            #pragma unroll
            for (int r = 0; r < 2; r++) {
                int n = n0 + r * 16;
                uint4 a4 = *(const uint4*)(s_an + (c * N_ + n) * 136 + jc * 8);
                float s = acc[r];
                s = fdot2(a4.x, t4.x, s);
                s = fdot2(a4.y, t4.y, s);
                s = fdot2(a4.z, t4.z, s);
                s = fdot2(a4.w, t4.w, s);
                acc[r] = s;
            }
        }
        #pragma unroll
        for (int r = 0; r < 2; r++) {
            int n = n0 + r * 16;
            float mk = s_mask[c][n];
            s_eat[c][h][n] = acc[r] + (1.0f - mk) * (-1.0e9f);
        }
    }
    __syncthreads();

    // ---- Phase E: softmax; write attn to global; store (am,am) f16 pairs ----
    if (tid < G_ * H_) {
        int c = tid >> 3, h = tid & 7;
        float e[N_];
        float m = -3.0e38f;
        #pragma unroll
        for (int n = 0; n < N_; n++) { e[n] = s_eat[c][h][n]; m = fmaxf(m, e[n]); }
        float sum = 0.f;
        #pragma unroll
        for (int n = 0; n < N_; n++) { float p = __expf(e[n] - m); e[n] = p; sum += p; }
        float inv = 1.0f / sum;
        u32* ampk = (u32*)&s_eat[c][h][0];
        float asum = 0.f;
        size_t off = ((size_t)(b * H_ + h) * C_ + (c0 + c)) * N_;
        #pragma unroll
        for (int n4 = 0; n4 < 8; n4++) {
            float4 w;
            w.x = e[n4 * 4]     * inv;
            w.y = e[n4 * 4 + 1] * inv;
            w.z = e[n4 * 4 + 2] * inv;
            w.w = e[n4 * 4 + 3] * inv;
            *(float4*)(attn_o + off + n4 * 4) = w;
            float am0 = w.x * s_mask[c][n4 * 4];
            float am1 = w.y * s_mask[c][n4 * 4 + 1];
            float am2 = w.z * s_mask[c][n4 * 4 + 2];
            float am3 = w.w * s_mask[c][n4 * 4 + 3];
            asum += am0 + am1 + am2 + am3;
            ampk[n4 * 4]     = pkrtz(am0, am0);
            ampk[n4 * 4 + 1] = pkrtz(am1, am1);
            ampk[n4 * 4 + 2] = pkrtz(am2, am2);
            ampk[n4 * 4 + 3] = pkrtz(am3, am3);
        }
        s_asum[c][h] = asum;
    }
    __syncthreads();

    // ---- Phase F: s[c,h,j] = sum_n am*an via v_pk_fma_f16 ----
    // thread (c, h, jg): 8 j's (1 uint4 per n). At T=512 TWO waves share each
    // c-slab, so the s-output overlay into s_an needs an explicit barrier
    // between the read-accumulate and the store (cross-wave WAR).
    {
        int c = tid >> 7, h = (tid >> 4) & 7, jg = tid & 15;
        const u32* ampk = (const u32*)&s_eat[c][h][0];
        __half2 acc2[4];
        #pragma unroll
        for (int i = 0; i < 4; i++) acc2[i] = __float2half2_rn(0.f);
        #pragma unroll 4
        for (int n = 0; n < N_; n++) {
            u32 am2 = ampk[n];
            uint4 a0 = *(const uint4*)(s_an + (c * N_ + n) * 136 + jg * 8);
            acc2[0] = fma2(a0.x, am2, acc2[0]);
            acc2[1] = fma2(a0.y, am2, acc2[1]);
            acc2[2] = fma2(a0.z, am2, acc2[2]);
            acc2[3] = fma2(a0.w, am2, acc2[3]);
        }
        __syncthreads();                        // all an-reads done before s-writes
        float* srow = (float*)(s_an + c * (N_ * 136)) + h * 132 + jg * 8;
        float2 f0 = __half22float2(acc2[0]);
        float2 f1 = __half22float2(acc2[1]);
        float2 f2 = __half22float2(acc2[2]);
        float2 f3 = __half22float2(acc2[3]);
        *(float4*)(srow + 0) = make_float4(f0.x, f0.y, f1.x, f1.y);
        *(float4*)(srow + 4) = make_float4(f2.x, f2.y, f3.x, f3.y);
    }
    __syncthreads();

    // ---- Phase G: ctx partials — Wv loaded AT USE (r8 lesson: no
    // live-across-phases weight array). thread (op, js4, ch) as in B. ----
    {
        const int op  = tid & 63;
        const int js4 = (tid >> 6) & 3;
        const int ch  = tid >> 8;
        const int cA  = ch * 2, cB = cA + 1;
        const int h   = op >> 3;              // od = 2op -> head = od/16
        const float* scA = (const float*)(s_an + cA * (N_ * 136));
        const float* scB = (const float*)(s_an + cB * (N_ * 136));
        float a0A = 0.f, a1A = 0.f, a0B = 0.f, a1B = 0.f;
        #pragma unroll
        for (int i4 = 0; i4 < 8; i4++) {
            int j = js4 * 32 + i4 * 4;
            float2 w0 = ((const float2*)(wv_g + (size_t)(j + 0) * D_))[op];
            float2 w1 = ((const float2*)(wv_g + (size_t)(j + 1) * D_))[op];
            float2 w2 = ((const float2*)(wv_g + (size_t)(j + 2) * D_))[op];
            float2 w3 = ((const float2*)(wv_g + (size_t)(j + 3) * D_))[op];
            float4 sA = *(const float4*)&scA[h * 132 + j];
            float4 sB = *(const float4*)&scB[h * 132 + j];
            a0A = fmaf(sA.x, w0.x, a0A); a1A = fmaf(sA.x, w0.y, a1A);
            a0A = fmaf(sA.y, w1.x, a0A); a1A = fmaf(sA.y, w1.y, a1A);
            a0A = fmaf(sA.z, w2.x, a0A); a1A = fmaf(sA.z, w2.y, a1A);
            a0A = fmaf(sA.w, w3.x, a0A); a1A = fmaf(sA.w, w3.y, a1A);
            a0B = fmaf(sB.x, w0.x, a0B); a1B = fmaf(sB.x, w0.y, a1B);
            a0B = fmaf(sB.y, w1.x, a0B); a1B = fmaf(sB.y, w1.y, a1B);
            a0B = fmaf(sB.z, w2.x, a0B); a1B = fmaf(sB.z, w2.y, a1B);
            a0B = fmaf(sB.w, w3.x, a0B); a1B = fmaf(sB.w, w3.y, a1B);
        }
        float* s_gp = (float*)s_ts;       // t32 dead after D; B-partials dead after B2
        *(float2*)&s_gp[(js4 * 4 + cA) * D_ + 2 * op] = make_float2(a0A, a1A);
        *(float2*)&s_gp[(js4 * 4 + cB) * D_ + 2 * op] = make_float2(a0B, a1B);
    }
    __syncthreads();

    // ---- Phase G2: reduce partials + bias + residual -> ctx; single pass ----
    {
        const float* s_gp = (const float*)s_ts;
        int c = tid >> 7, od = tid & 127;
        int h = od >> 4;
        float sum = s_gp[(0 * 4 + c) * D_ + od] + s_gp[(1 * 4 + c) * D_ + od]
                  + s_gp[(2 * 4 + c) * D_ + od] + s_gp[(3 * 4 + c) * D_ + od];
        float r0 = sum + s_asum[c][h] * bv_g[od] + s_q[c][h * 20 + (od & 15)];
        ctx_o[((size_t)(b * C_ + c0 + c)) * D_ + od] = r0;
    }
}

extern "C" void kernel_launch(void* const* d_in, const int* in_sizes, int n_in,
                              void* d_out, int out_size, void* d_ws, size_t ws_size,
                              hipStream_t stream) {
    const float* aq   = (const float*)d_in[0];
    const float* an   = (const float*)d_in[1];
    const float* dist = (const float*)d_in[2];
    const float* mask = (const float*)d_in[3];
    const float* wq   = (const float*)d_in[4];
    const float* bq   = (const float*)d_in[5];
    const float* wk   = (const float*)d_in[6];
    // d_in[7] = bk: constant over n -> cancels exactly in softmax.
    const float* wv   = (const float*)d_in[8];
    const float* bv   = (const float*)d_in[9];
    const float* wf   = (const float*)d_in[10];
    const float* bfb  = (const float*)d_in[11];

    float* attn_o = (float*)d_out;
    float* ctx_o  = attn_o + (size_t)B_ * H_ * C_ * N_;

    dim3 grid(B_ * C_ / G_), block(T_);
    hipLaunchKernelGGL(la_kernel, grid, block, 0, stream,
                       aq, an, dist, mask, wq, bq, wk, wv, bv, wf, bfb,
                       attn_o, ctx_o);
}

// Round 5
// 421.330 us; speedup vs baseline: 1.0786x; 1.0786x over previous
//
#include <hip/hip_runtime.h>
#include <hip/hip_fp16.h>
#include <cstdint>

// LocalAttention fused kernel, round 10: revert to T=256 (r8 base, ~152us) and
// replace Phase D's scalar dot2 contraction with MFMA 16x16x32_f16.
//
// Round-9 post-mortem: T=512 doubled occupancy (31->62.6%) but VALUBusy stayed
// ~35% and WRITE_SIZE showed a fresh spill (84MB, VGPR=40) under the (512,6)
// cap -> net regression. The unchanged-VALUBusy-at-2x-waves observation says
// the kernel is NOT wave-latency-bound: it is LDS-PIPE-ISSUE-bound. Phase D
// issued 80 ds_read_b128/thread (an rows re-read by all 8 h-threads: 8x
// redundancy), ~960 LDS-pipe cyc/wave vs ~128 VALU cyc -> ~25us of pure LDS
// issue. MFMA amortizes the redundancy in-register:
//   per c (one wave): energy[16(h pad),32(n)] = t[16,128] x B[128,32],
//   B[k=j][col=n] = an[n][j]  (an rows ARE the B fragments, j contiguous).
//   4 K-steps x 2 n-tiles = 8 mfma; LDS: 12 b128/wave vs 80 b128/thread.
// Fragment layouts (calculator convention, C/D measured on gfx950):
//   A: lane l -> row l&15 (clamped &7), k = (l>>4)*8+i  (1 b128 from t32 row)
//   B: lane l -> col l&15, k = (l>>4)*8+i               (1 b128 from an row)
//   D: col n = l&15, row h = (l>>4)*4+reg (lanes 0..31 valid, h 0..7)
// Phase F stays scalar (its MFMA form needs n-contiguous an = transpose; next
// round if D's layout verifies).
//
// Algebra (exact in real arithmetic):
//   energy[h,n] = sum_j an[n,j] * t[h,j],  t[h,j] = 0.25 * sum_d' q[h,d'] Wk[j,h*16+d']
//     (bk constant over n -> cancels in softmax)
//   ctx[h,d'] = sum_j s[h,j] * Wv[j,h*16+d'] + (sum_n attnm[h,n]) * bv[h,d']
//     with s[h,:] = attnm[h,:] @ an

#define B_ 16
#define C_ 1024
#define N_ 32
#define H_ 8
#define D_ 128
#define G_ 4
#define T_ 256

typedef unsigned short u16;
typedef unsigned int u32;
typedef __fp16 hw2 __attribute__((ext_vector_type(2)));   // matches builtin sigs
typedef __fp16 f16x8 __attribute__((ext_vector_type(8)));
typedef float  f32x4 __attribute__((ext_vector_type(4)));

__device__ __forceinline__ u32 pkrtz(float a, float b) {
    hw2 r = __builtin_amdgcn_cvt_pkrtz(a, b);
    return __builtin_bit_cast(u32, r);
}
__device__ __forceinline__ __half2 fma2(u32 a, u32 b, __half2 c) {
    return __hfma2(__builtin_bit_cast(__half2, a),
                   __builtin_bit_cast(__half2, b), c);
}
__device__ __forceinline__ float swishf(float x) {
    float s = __builtin_amdgcn_rcpf(1.0f + __expf(-x));
    return x * s;
}

__global__ __launch_bounds__(T_, 3)
void la_kernel(const float* __restrict__ aq_g,  const float* __restrict__ an_g,
               const float* __restrict__ dist_g, const float* __restrict__ mask_g,
               const float* __restrict__ wq_g,  const float* __restrict__ bq_g,
               const float* __restrict__ wk_g,
               const float* __restrict__ wv_g,  const float* __restrict__ bv_g,
               const float* __restrict__ wf_g,  const float* __restrict__ bfb_g,
               float* __restrict__ attn_o, float* __restrict__ ctx_o)
{
    // LDS: 34816(s_an) + 8704(s_ts) + 2560(s_q) + 4224(s_eat) + 512+512+128+512+512
    //    = 52,480 B  -> 3 blocks/CU
    __shared__ __align__(16) u16   s_an[G_ * N_ * 136];   // gated neighbors f16; per-c f32 s-slab after F
    __shared__ __align__(16) u32   s_ts[G_ * H_ * 68];    // B-partials(f32) / t32(f16 pairs) / G-partials(f32)
    __shared__ __align__(16) float s_q[G_][H_ * 20];      // projected query (unscaled), head stride 20
    __shared__ __align__(16) float s_eat[G_][H_][33];     // aq staging (ph0..B) -> energy f32 (D/E) -> am pairs (F)
    __shared__ float s_dist[G_][N_];
    __shared__ float s_mask[G_][N_];
    __shared__ float s_asum[G_][H_];
    __shared__ __align__(16) float s_wf[D_];
    __shared__ __align__(16) float s_bfb[D_];

    const int tid = threadIdx.x;
    const int b   = blockIdx.x >> 8;          // 256 c-groups per b
    const int c0  = (blockIdx.x & 255) << 2;  // G_=4 c's per block

    const int op = tid & 63;                  // output-pair index (od = 2*op)
    const int js = tid >> 6;                  // j-slice index (rows js*32 .. js*32+31)

    // ---- Prefetch Wq slice into registers (overlaps Phase A an-stream) ----
    float2 wq2[32];
    #pragma unroll
    for (int i = 0; i < 32; i++)
        wq2[i] = ((const float2*)(wq_g + (size_t)(js * 32 + i) * D_))[op];

    // ---- Phase 0: stage small tensors ----
    float* s_aqf = (float*)s_eat;             // [c*128+d], first 2048 B of the s_eat slab
    if (tid < D_) {
        s_wf[tid]  = wf_g[tid];
        s_bfb[tid] = bfb_g[tid];
        int c = tid >> 5, n = tid & 31;
        int gi = (b * C_ + c0 + c) * N_ + n;
        s_dist[c][n] = dist_g[gi];
        s_mask[c][n] = mask_g[gi];
    }
    {
        s_aqf[tid] = aq_g[(b * C_ + c0 + (tid >> 7)) * D_ + (tid & 127)];
        int i2 = tid + 256;
        s_aqf[i2] = aq_g[(b * C_ + c0 + (i2 >> 7)) * D_ + (i2 & 127)];
    }
    __syncthreads();

    // ---- Phase A: stream + swish-gate atom_neighbor -> s_an (f16 pairs) ----
    {
        const float4* gan = (const float4*)(an_g + (size_t)(b * C_ + c0) * N_ * D_);
        #pragma unroll
        for (int k = 0; k < 16; k++) {
            int ci = k * T_ + tid;                  // float4 chunk index, 4096 total
            float4 v = gan[ci];
            int d4 = ci & 31, n = (ci >> 5) & 31, c = ci >> 10;
            float dist = s_dist[c][n];
            int d0 = d4 << 2;
            float4 wf = *(const float4*)&s_wf[d0];
            float4 bb = *(const float4*)&s_bfb[d0];
            float g0 = swishf(fmaf(dist, wf.x, bb.x));
            float g1 = swishf(fmaf(dist, wf.y, bb.y));
            float g2 = swishf(fmaf(dist, wf.z, bb.z));
            float g3 = swishf(fmaf(dist, wf.w, bb.w));
            u32 o0 = pkrtz(v.x * g0, v.y * g1);
            u32 o1 = pkrtz(v.z * g2, v.w * g3);
            *(uint2*)(s_an + (c * N_ + n) * 136 + d0) = make_uint2(o0, o1);
        }
    }

    // ---- Phase B: q partials — thread (op,js) covers j in [js*32, js*32+32) ----
    {
        float acc0[G_], acc1[G_];
        #pragma unroll
        for (int c = 0; c < G_; c++) { acc0[c] = 0.f; acc1[c] = 0.f; }
        #pragma unroll
        for (int i4 = 0; i4 < 8; i4++) {
            #pragma unroll
            for (int c = 0; c < G_; c++) {
                float4 a4 = *(const float4*)&s_aqf[c * D_ + js * 32 + i4 * 4];
                float2 w0 = wq2[i4 * 4], w1 = wq2[i4 * 4 + 1];
                float2 w2 = wq2[i4 * 4 + 2], w3 = wq2[i4 * 4 + 3];
                acc0[c] = fmaf(a4.x, w0.x, acc0[c]); acc1[c] = fmaf(a4.x, w0.y, acc1[c]);
                acc0[c] = fmaf(a4.y, w1.x, acc0[c]); acc1[c] = fmaf(a4.y, w1.y, acc1[c]);
                acc0[c] = fmaf(a4.z, w2.x, acc0[c]); acc1[c] = fmaf(a4.z, w2.y, acc1[c]);
                acc0[c] = fmaf(a4.w, w3.x, acc0[c]); acc1[c] = fmaf(a4.w, w3.y, acc1[c]);
            }
        }
        float* s_part = (float*)s_ts;   // [js][c][128] scratch, 8 KB
        #pragma unroll
        for (int c = 0; c < G_; c++) {
            *(float2*)&s_part[(js * G_ + c) * D_ + 2 * op] = make_float2(acc0[c], acc1[c]);
        }
    }
    __syncthreads();

    // ---- Phase B2: reduce partials -> s_q (head stride 20) ----
    {
        const float* s_part = (const float*)s_ts;
        #pragma unroll
        for (int r = 0; r < 2; r++) {
            int lin = r * 256 + tid;
            int c = lin >> 7, od = lin & 127;
            float sum = s_part[(0 * G_ + c) * D_ + od] + s_part[(1 * G_ + c) * D_ + od]
                      + s_part[(2 * G_ + c) * D_ + od] + s_part[(3 * G_ + c) * D_ + od];
            s_q[c][(od >> 4) * 20 + (od & 15)] = sum + bq_g[od];
        }
    }
    __syncthreads();

    // ---- Phase C: t[c,h,j] = 0.25*sum_d' q*Wk, packed f16 pairs into t32 ----
    // thread (h, jb) owns j in {2jb, 2jb+1, 64+2jb, 64+2jb+1}
    {
        u32* t32 = s_ts;                   // [c*8+h][68] u32 (f16 pairs), 8.7 KB
        int h = tid & 7, jb = tid >> 3;    // jb in 0..31
        float wk[4][16];
        #pragma unroll
        for (int jj = 0; jj < 4; jj++) {
            int j = 2 * jb + (jj & 1) + (jj >> 1) * 64;
            const float4* pk = (const float4*)(wk_g + j * D_ + h * 16);
            float4 k0 = pk[0], k1 = pk[1], k2 = pk[2], k3 = pk[3];
            wk[jj][0]  = k0.x; wk[jj][1]  = k0.y; wk[jj][2]  = k0.z; wk[jj][3]  = k0.w;
            wk[jj][4]  = k1.x; wk[jj][5]  = k1.y; wk[jj][6]  = k1.z; wk[jj][7]  = k1.w;
            wk[jj][8]  = k2.x; wk[jj][9]  = k2.y; wk[jj][10] = k2.z; wk[jj][11] = k2.w;
            wk[jj][12] = k3.x; wk[jj][13] = k3.y; wk[jj][14] = k3.z; wk[jj][15] = k3.w;
        }
        #pragma unroll
        for (int c = 0; c < G_; c++) {
            const float4* pq = (const float4*)&s_q[c][h * 20];   // 80B base: 16B aligned
            float4 q0 = pq[0], q1 = pq[1], q2 = pq[2], q3 = pq[3];
            float acc[4];
            #pragma unroll
            for (int jj = 0; jj < 4; jj++) {
                float a = 0.f;
                a = fmaf(q0.x, wk[jj][0],  a);
                a = fmaf(q0.y, wk[jj][1],  a);
                a = fmaf(q0.z, wk[jj][2],  a);
                a = fmaf(q0.w, wk[jj][3],  a);
                a = fmaf(q1.x, wk[jj][4],  a);
                a = fmaf(q1.y, wk[jj][5],  a);
                a = fmaf(q1.z, wk[jj][6],  a);
                a = fmaf(q1.w, wk[jj][7],  a);
                a = fmaf(q2.x, wk[jj][8],  a);
                a = fmaf(q2.y, wk[jj][9],  a);
                a = fmaf(q2.z, wk[jj][10], a);
                a = fmaf(q2.w, wk[jj][11], a);
                a = fmaf(q3.x, wk[jj][12], a);
                a = fmaf(q3.y, wk[jj][13], a);
                a = fmaf(q3.z, wk[jj][14], a);
                a = fmaf(q3.w, wk[jj][15], a);
                acc[jj] = a * 0.25f;
            }
            t32[(c * 8 + h) * 68 + jb]      = pkrtz(acc[0], acc[1]);  // pair jb    (j=2jb,2jb+1)
            t32[(c * 8 + h) * 68 + 32 + jb] = pkrtz(acc[2], acc[3]);  // pair jb+32 (j=64+2jb,..)
        }
    }
    __syncthreads();

    // ---- Phase D: energy via MFMA 16x16x32_f16; one wave per c ----
    // A = t[16(h pad),128(j)]; B[k=j][col=n] = an[n][j] (rows ARE the frags).
    // 4 K-steps x 2 n-tiles, acc in f32x4. Lanes 0..31 hold valid h 0..7.
    {
        const int c    = js;                 // wave id = c
        const int lane = tid & 63;
        const int row  = lane & 15;
        const int kg   = lane >> 4;
        const u32* t32 = s_ts;
        f32x4 acc0 = {0.f, 0.f, 0.f, 0.f};
        f32x4 acc1 = {0.f, 0.f, 0.f, 0.f};
        #pragma unroll
        for (int kk = 0; kk < 4; kk++) {
            uint4 ar  = *(const uint4*)(t32 + (c * 8 + (row & 7)) * 68 + kk * 16 + kg * 4);
            uint4 b0r = *(const uint4*)(s_an + (c * N_ + row) * 136 + kk * 32 + kg * 8);
            uint4 b1r = *(const uint4*)(s_an + (c * N_ + 16 + row) * 136 + kk * 32 + kg * 8);
            f16x8 af = __builtin_bit_cast(f16x8, ar);
            acc0 = __builtin_amdgcn_mfma_f32_16x16x32_f16(af, __builtin_bit_cast(f16x8, b0r), acc0, 0, 0, 0);
            acc1 = __builtin_amdgcn_mfma_f32_16x16x32_f16(af, __builtin_bit_cast(f16x8, b1r), acc1, 0, 0, 0);
        }
        if (lane < 32) {
            #pragma unroll
            for (int r = 0; r < 4; r++) {
                int h = kg * 4 + r;          // kg in {0,1} -> h 0..7
                int n0 = row, n1 = 16 + row;
                float mk0 = s_mask[c][n0];
                float mk1 = s_mask[c][n1];
                s_eat[c][h][n0] = acc0[r] + (1.0f - mk0) * (-1.0e9f);
                s_eat[c][h][n1] = acc1[r] + (1.0f - mk1) * (-1.0e9f);
            }
        }
    }
    __syncthreads();

    // ---- Phase E: softmax; write attn to global; store (am,am) f16 pairs ----
    if (tid < G_ * H_) {
        int c = tid >> 3, h = tid & 7;
        float e[N_];
        float m = -3.0e38f;
        #pragma unroll
        for (int n = 0; n < N_; n++) { e[n] = s_eat[c][h][n]; m = fmaxf(m, e[n]); }
        float sum = 0.f;
        #pragma unroll
        for (int n = 0; n < N_; n++) { float p = __expf(e[n] - m); e[n] = p; sum += p; }
        float inv = 1.0f / sum;
        u32* ampk = (u32*)&s_eat[c][h][0];
        float asum = 0.f;
        size_t off = ((size_t)(b * H_ + h) * C_ + (c0 + c)) * N_;
        #pragma unroll
        for (int n4 = 0; n4 < 8; n4++) {
            float4 w;
            w.x = e[n4 * 4]     * inv;
            w.y = e[n4 * 4 + 1] * inv;
            w.z = e[n4 * 4 + 2] * inv;
            w.w = e[n4 * 4 + 3] * inv;
            *(float4*)(attn_o + off + n4 * 4) = w;
            float am0 = w.x * s_mask[c][n4 * 4];
            float am1 = w.y * s_mask[c][n4 * 4 + 1];
            float am2 = w.z * s_mask[c][n4 * 4 + 2];
            float am3 = w.w * s_mask[c][n4 * 4 + 3];
            asum += am0 + am1 + am2 + am3;
            ampk[n4 * 4]     = pkrtz(am0, am0);
            ampk[n4 * 4 + 1] = pkrtz(am1, am1);
            ampk[n4 * 4 + 2] = pkrtz(am2, am2);
            ampk[n4 * 4 + 3] = pkrtz(am3, am3);
        }
        s_asum[c][h] = asum;
    }
    __syncthreads();

    // ---- Phase F: s[c,h,j] = sum_n am*an via v_pk_fma_f16 (f16x2 acc) ----
    // Output s (f32) goes into this c's slab of s_an: one wave per c, write
    // instructions follow all read instructions in wave program order -> safe.
    {
        int c = tid >> 6, h = (tid >> 3) & 7, jg = tid & 7;
        const u32* ampk = (const u32*)&s_eat[c][h][0];
        __half2 acc2[8];
        #pragma unroll
        for (int i = 0; i < 8; i++) acc2[i] = __float2half2_rn(0.f);
        #pragma unroll 4
        for (int n = 0; n < N_; n++) {
            u32 am2 = ampk[n];
            const uint4* arow = (const uint4*)(s_an + (c * N_ + n) * 136 + jg * 16);
            uint4 a0 = arow[0], a1 = arow[1];
            acc2[0] = fma2(a0.x, am2, acc2[0]);
            acc2[1] = fma2(a0.y, am2, acc2[1]);
            acc2[2] = fma2(a0.z, am2, acc2[2]);
            acc2[3] = fma2(a0.w, am2, acc2[3]);
            acc2[4] = fma2(a1.x, am2, acc2[4]);
            acc2[5] = fma2(a1.y, am2, acc2[5]);
            acc2[6] = fma2(a1.z, am2, acc2[6]);
            acc2[7] = fma2(a1.w, am2, acc2[7]);
        }
        float* srow = (float*)(s_an + c * (N_ * 136)) + h * 132 + jg * 16;
        #pragma unroll
        for (int p = 0; p < 4; p++) {
            float2 lo = __half22float2(acc2[p * 2]);
            float2 hi = __half22float2(acc2[p * 2 + 1]);
            *(float4*)(srow + p * 4) = make_float4(lo.x, lo.y, hi.x, hi.y);
        }
    }
    __syncthreads();

    // ---- Phase G: ctx partials — Wv loaded AT USE (r8 lesson: no
    // live-across-phases weight array; L1/L2-warm). ----
    {
        int h = op >> 3;                  // od = 2*op -> head = od/16
        float acc0[G_], acc1[G_];
        #pragma unroll
        for (int c = 0; c < G_; c++) { acc0[c] = 0.f; acc1[c] = 0.f; }
        #pragma unroll
        for (int i4 = 0; i4 < 8; i4++) {
            float2 w0 = ((const float2*)(wv_g + (size_t)(js * 32 + i4 * 4 + 0) * D_))[op];
            float2 w1 = ((const float2*)(wv_g + (size_t)(js * 32 + i4 * 4 + 1) * D_))[op];
            float2 w2 = ((const float2*)(wv_g + (size_t)(js * 32 + i4 * 4 + 2) * D_))[op];
            float2 w3 = ((const float2*)(wv_g + (size_t)(js * 32 + i4 * 4 + 3) * D_))[op];
            #pragma unroll
            for (int c = 0; c < G_; c++) {
                const float* sc_ = (const float*)(s_an + c * (N_ * 136));
                float4 s4 = *(const float4*)&sc_[h * 132 + js * 32 + i4 * 4];
                acc0[c] = fmaf(s4.x, w0.x, acc0[c]); acc1[c] = fmaf(s4.x, w0.y, acc1[c]);
                acc0[c] = fmaf(s4.y, w1.x, acc0[c]); acc1[c] = fmaf(s4.y, w1.y, acc1[c]);
                acc0[c] = fmaf(s4.z, w2.x, acc0[c]); acc1[c] = fmaf(s4.z, w2.y, acc1[c]);
                acc0[c] = fmaf(s4.w, w3.x, acc0[c]); acc1[c] = fmaf(s4.w, w3.y, acc1[c]);
            }
        }
        float* s_gp = (float*)s_ts;       // 8 KB scratch, t32 dead after D
        #pragma unroll
        for (int c = 0; c < G_; c++) {
            *(float2*)&s_gp[(js * G_ + c) * D_ + 2 * op] = make_float2(acc0[c], acc1[c]);
        }
    }
    __syncthreads();

    // ---- Phase G2: reduce partials + bias + residual -> ctx ----
    {
        const float* s_gp = (const float*)s_ts;
        #pragma unroll
        for (int r = 0; r < 2; r++) {
            int lin = r * 256 + tid;
            int c = lin >> 7, od = lin & 127;
            int h = od >> 4;
            float sum = s_gp[(0 * G_ + c) * D_ + od] + s_gp[(1 * G_ + c) * D_ + od]
                      + s_gp[(2 * G_ + c) * D_ + od] + s_gp[(3 * G_ + c) * D_ + od];
            float r0 = sum + s_asum[c][h] * bv_g[od] + s_q[c][h * 20 + (od & 15)];
            ctx_o[((size_t)(b * C_ + c0 + c)) * D_ + od] = r0;
        }
    }
}

extern "C" void kernel_launch(void* const* d_in, const int* in_sizes, int n_in,
                              void* d_out, int out_size, void* d_ws, size_t ws_size,
                              hipStream_t stream) {
    const float* aq   = (const float*)d_in[0];
    const float* an   = (const float*)d_in[1];
    const float* dist = (const float*)d_in[2];
    const float* mask = (const float*)d_in[3];
    const float* wq   = (const float*)d_in[4];
    const float* bq   = (const float*)d_in[5];
    const float* wk   = (const float*)d_in[6];
    // d_in[7] = bk: constant over n -> cancels exactly in softmax.
    const float* wv   = (const float*)d_in[8];
    const float* bv   = (const float*)d_in[9];
    const float* wf   = (const float*)d_in[10];
    const float* bfb  = (const float*)d_in[11];

    float* attn_o = (float*)d_out;
    float* ctx_o  = attn_o + (size_t)B_ * H_ * C_ * N_;

    dim3 grid(B_ * C_ / G_), block(T_);
    hipLaunchKernelGGL(la_kernel, grid, block, 0, stream,
                       aq, an, dist, mask, wq, bq, wk, wv, bv, wf, bfb,
                       attn_o, ctx_o);
}